// Round 4
// baseline (152.555 us; speedup 1.0000x reference)
//
#include <hip/hip_runtime.h>
#include <math.h>

#ifndef __has_builtin
#define __has_builtin(x) 0
#endif

#define NPTS   131072
#define FCH    16
#define CSND   343.0f
#define PB     16           // points per workgroup pass
#define BLOCK  256          // 4 waves
#define GRID   1024         // 4 WG/CU * 256 CUs
#define NBLK   (NPTS / PB)  // 8192

typedef _Float16 half8 __attribute__((ext_vector_type(8)));
typedef _Float16 half2v __attribute__((ext_vector_type(2)));
typedef float    f32x4 __attribute__((ext_vector_type(4)));

static __device__ __forceinline__ unsigned pack2(float a, float b) {
#if __has_builtin(__builtin_amdgcn_cvt_pkrtz)
  return __builtin_bit_cast(unsigned, __builtin_amdgcn_cvt_pkrtz(a, b));
#else
  half2v v; v[0] = (_Float16)a; v[1] = (_Float16)b;
  return __builtin_bit_cast(unsigned, v);
#endif
}

static __device__ __forceinline__ float mytanh(float x) {
  float ax = fabsf(x);
  float e  = __expf(-2.0f * ax);
  float r  = (1.0f - e) * __builtin_amdgcn_rcpf(1.0f + e);
  return copysignf(r, x);
}

// LDS (33 KB total -> 4 WG/CU; W2/W3 fragments live in registers):
//   s_A[80][64] dw : A-matrix f16, rows v*16+p (v=0..4: h1,d0,d1,d2,c1),
//                    chunk c of 8 k-vals stored at (c ^ (row&15)) -> b128 ok
//   s_HG[32][64] dw: u16 rows 0..15 = h2[p][j], 16..31 = G[p][j], same swizzle
//   s_Y[2][16][33] f32: y then lap
// Barriers: 3 per pass. A->s_A | bar1 | B reads s_A, C->s_HG | bar2 |
// D reads s_HG ->s_Y | bar3 | E reads s_Y. Each cross-wave write->read pair
// spans >=1 barrier; buffer separation removes the old WAR barriers.

__global__ __launch_bounds__(BLOCK, 4) void helmholtz_kernel(
    const float* __restrict__ x,      // [N,3]
    const float* __restrict__ omega,  // [16]
    const float* __restrict__ W1,     // [3,128]
    const float* __restrict__ b1,     // [128]
    const float* __restrict__ W2,     // [128,128]
    const float* __restrict__ b2,     // [128]
    const float* __restrict__ W3,     // [128,32]
    const float* __restrict__ b3,     // [32]
    float* __restrict__ out)
{
  __shared__ unsigned s_A[80 * 64];     // 20 KB
  __shared__ unsigned s_HG[32 * 64];    //  8 KB
  __shared__ float    s_Y[2 * 16 * 33]; //  4.125 KB

  const int tid  = threadIdx.x;
  const int w    = tid >> 6;   // wave 0..3
  const int l    = tid & 63;
  const int col  = l & 15;
  const int quad = l >> 4;

  // ---- persistent per-thread registers ----
  // phase A: thread handles input-unit pair i0=2*i2, i1=2*i2+1
  const int i2 = tid & 63;
  const float a0x = W1[2 * i2],       a0y = W1[128 + 2 * i2],  a0z = W1[256 + 2 * i2];
  const float a1x = W1[2 * i2 + 1],   a1y = W1[129 + 2 * i2],  a1z = W1[257 + 2 * i2];
  const float bb0 = b1[2 * i2],       bb1 = b1[2 * i2 + 1];
  const float wsq0 = a0x * a0x + a0y * a0y + a0z * a0z;
  const float wsq1 = a1x * a1x + a1y * a1y + a1z * a1z;

  // phase B: W2^T fragments, loop-invariant -> registers (32 VGPRs).
  // frag[ntl][ks][j] = W2[k=ks*32+quad*8+j][n=(2w+ntl)*16+col]
  half8 w2f[2][4];
#pragma unroll
  for (int ntl = 0; ntl < 2; ntl++) {
    const int n = (2 * w + ntl) * 16 + col;
#pragma unroll
    for (int ks = 0; ks < 4; ks++) {
      half8 f;
#pragma unroll
      for (int j = 0; j < 8; j++)
        f[j] = (_Float16)W2[(ks * 32 + (quad << 3) + j) * 128 + n];
      w2f[ntl][ks] = f;
    }
  }
  // phase D: W3^T fragment for this wave's tile (16 VGPRs).
  half8 w3f[4];
  {
    const int n = (w & 1) * 16 + col;
#pragma unroll
    for (int ks = 0; ks < 4; ks++) {
      half8 f;
#pragma unroll
      for (int j = 0; j < 8; j++)
        f[j] = (_Float16)W3[(ks * 32 + (quad << 3) + j) * 32 + n];
      w3f[ks] = f;
    }
  }

  // phase C: wave w owns output cols j = w*32 + col and + 16
  const float b2r0 = b2[w * 32 + col];
  const float b2r1 = b2[w * 32 + 16 + col];
  // phase E: thread owns (point p = tid>>4, channel cE = (tid&15)+1)
  const bool  activeE = (tid & 15) < 15;
  const int   cE = (tid & 15) + 1;
  float k2E = 0.0f, b3a = 0.0f, b3b = 0.0f;
  if (activeE) {
    float om = omega[cE] * (1.0f / CSND);
    k2E = om * om;
    b3a = b3[cE];
    b3b = b3[cE + 16];
  }

  float wsum = 0.0f;

  for (int blk = blockIdx.x; blk < NBLK; blk += gridDim.x) {
    const int pbase = blk * PB;

    // ---- phase A: layer 1 + 5 layer-2 input vectors -> s_A (f16, swizzled) ----
#pragma unroll
    for (int it = 0; it < 4; it++) {
      int p = w * 4 + it;
      const float* xp = x + (size_t)(pbase + p) * 3;
      float x0 = xp[0], x1 = xp[1], x2 = xp[2];
      float z0 = fmaf(x0, a0x, fmaf(x1, a0y, fmaf(x2, a0z, bb0)));
      float z1 = fmaf(x0, a1x, fmaf(x1, a1y, fmaf(x2, a1z, bb1)));
      float t0 = mytanh(z0), t1 = mytanh(z1);
      float s0 = 1.0f - t0 * t0, s1 = 1.0f - t1 * t1;
      unsigned u_h  = pack2(t0, t1);
      unsigned u_d0 = pack2(s0 * a0x, s1 * a1x);
      unsigned u_d1 = pack2(s0 * a0y, s1 * a1y);
      unsigned u_d2 = pack2(s0 * a0z, s1 * a1z);
      unsigned u_c  = pack2(-2.0f * t0 * s0 * wsq0, -2.0f * t1 * s1 * wsq1);
      int dcol = (((i2 >> 2) ^ p) << 2) + (i2 & 3);
      s_A[(p)      * 64 + dcol] = u_h;
      s_A[(16 + p) * 64 + dcol] = u_d0;
      s_A[(32 + p) * 64 + dcol] = u_d1;
      s_A[(48 + p) * 64 + dcol] = u_d2;
      s_A[(64 + p) * 64 + dcol] = u_c;
    }
    __syncthreads();  // bar1

    // ---- phase B: step-2 GEMM [80 x 128] x [128 x 128], B-frags in regs ----
    f32x4 acc[5][2];
#pragma unroll
    for (int mt = 0; mt < 5; mt++)
#pragma unroll
      for (int ntl = 0; ntl < 2; ntl++)
        acc[mt][ntl] = (f32x4){0.0f, 0.0f, 0.0f, 0.0f};

#pragma unroll
    for (int mt = 0; mt < 5; mt++) {
      int m = mt * 16 + col;
#pragma unroll
      for (int ks = 0; ks < 4; ks++) {
        int c = (ks * 4 + quad) ^ col;
        half8 af = *(const half8*)&s_A[m * 64 + (c << 2)];
        acc[mt][0] = __builtin_amdgcn_mfma_f32_16x16x32_f16(af, w2f[0][ks], acc[mt][0], 0, 0, 0);
        acc[mt][1] = __builtin_amdgcn_mfma_f32_16x16x32_f16(af, w2f[1][ks], acc[mt][1], 0, 0, 0);
      }
    }

    // ---- phase C: layer-2 elementwise in registers; write h2/G f16 -> s_HG ----
    {
      _Float16* hg = (_Float16*)s_HG;
#pragma unroll
      for (int ntl = 0; ntl < 2; ntl++) {
        int j = (2 * w + ntl) * 16 + col;
        int chunkj = j >> 3;
        float b2v = ntl ? b2r1 : b2r0;
#pragma unroll
        for (int r = 0; r < 4; r++) {
          int p = quad * 4 + r;
          float z2 = acc[0][ntl][r] + b2v;
          float d0 = acc[1][ntl][r], d1 = acc[2][ntl][r], d2 = acc[3][ntl][r];
          float Av = acc[4][ntl][r];
          float t2 = mytanh(z2);
          float s2 = 1.0f - t2 * t2;
          float g  = s2 * (Av - 2.0f * t2 * (d0 * d0 + d1 * d1 + d2 * d2));
          int base = ((chunkj ^ p) << 3) + (j & 7);
          hg[p * 128 + base]        = (_Float16)t2;   // h2 rows 0..15
          hg[(16 + p) * 128 + base] = (_Float16)g;    // G  rows 16..31
        }
      }
    }
    __syncthreads();  // bar2

    // ---- phase D: step-3 GEMM [32 x 128] x [128 x 32]; one 16x16 tile/wave ----
    {
      int mtp = w >> 1, ntp = w & 1;
      int mrow = mtp * 16 + col;
      f32x4 dacc = (f32x4){0.0f, 0.0f, 0.0f, 0.0f};
#pragma unroll
      for (int ks = 0; ks < 4; ks++) {
        int ca = (ks * 4 + quad) ^ col;
        half8 af = *(const half8*)&s_HG[mrow * 64 + (ca << 2)];
        dacc = __builtin_amdgcn_mfma_f32_16x16x32_f16(af, w3f[ks], dacc, 0, 0, 0);
      }
      int base = mtp ? 528 : 0;   // y rows then lap rows
#pragma unroll
      for (int r = 0; r < 4; r++) {
        int p = quad * 4 + r;
        s_Y[base + p * 33 + ntp * 16 + col] = dacc[r];
      }
    }
    __syncthreads();  // bar3

    // ---- phase E: residual ----
    if (activeE) {
      int p = tid >> 4;
      float yre = s_Y[p * 33 + cE] + b3a;
      float yim = s_Y[p * 33 + cE + 16] + b3b;
      float lre = s_Y[528 + p * 33 + cE];
      float lim = s_Y[528 + p * 33 + cE + 16];
      float re = fmaf(k2E, yre, lre);
      float im = fmaf(k2E, yim, lim);
      wsum += re * re + im * im;
    }
    // no barrier needed: next phase A touches only s_A, whose last cross-wave
    // reads (phase B) were before bar2 of this pass.
  }

  // ---- final: wave reduce, one atomic per wave ----
#pragma unroll
  for (int off = 32; off > 0; off >>= 1)
    wsum += __shfl_down(wsum, off, 64);
  if (l == 0)
    atomicAdd(out, wsum * (1.0f / ((float)NPTS * (float)(FCH - 1))));
}

extern "C" void kernel_launch(void* const* d_in, const int* in_sizes, int n_in,
                              void* d_out, int out_size, void* d_ws, size_t ws_size,
                              hipStream_t stream) {
  const float* x     = (const float*)d_in[0];
  const float* omega = (const float*)d_in[1];
  const float* W1    = (const float*)d_in[2];
  const float* b1    = (const float*)d_in[3];
  const float* W2    = (const float*)d_in[4];
  const float* b2    = (const float*)d_in[5];
  const float* W3    = (const float*)d_in[6];
  const float* b3    = (const float*)d_in[7];
  float* out = (float*)d_out;

  (void)hipMemsetAsync(out, 0, sizeof(float), stream);
  helmholtz_kernel<<<GRID, BLOCK, 0, stream>>>(x, omega, W1, b1, W2, b2, W3, b3, out);
}

// Round 5
// 146.093 us; speedup vs baseline: 1.0442x; 1.0442x over previous
//
#include <hip/hip_runtime.h>
#include <math.h>

#ifndef __has_builtin
#define __has_builtin(x) 0
#endif

#define NPTS   131072
#define FCH    16
#define CSND   343.0f
#define PB     32           // points per workgroup pass
#define BLOCK  512          // 8 waves
#define GRID   512          // 2 WG/CU * 256 CUs
#define NBLK   (NPTS / PB)  // 4096

typedef _Float16 half8 __attribute__((ext_vector_type(8)));
typedef _Float16 half2v __attribute__((ext_vector_type(2)));
typedef float    f32x4 __attribute__((ext_vector_type(4)));

static __device__ __forceinline__ unsigned pack2(float a, float b) {
#if __has_builtin(__builtin_amdgcn_cvt_pkrtz)
  return __builtin_bit_cast(unsigned, __builtin_amdgcn_cvt_pkrtz(a, b));
#else
  half2v v; v[0] = (_Float16)a; v[1] = (_Float16)b;
  return __builtin_bit_cast(unsigned, v);
#endif
}

static __device__ __forceinline__ float mytanh(float x) {
  float ax = fabsf(x);
  float e  = __expf(-2.0f * ax);
  float r  = (1.0f - e) * __builtin_amdgcn_rcpf(1.0f + e);
  return copysignf(r, x);
}

// LDS (56 KB -> 2 WG/CU, 16 waves/CU; all weights register-resident):
//   s_A[160][64] dw : A f16, rows v*32+p (v=0..4: h1,d0,d1,d2,c1; p=0..31),
//                     chunk c of 8 k-vals at (c ^ (row&15)) -> conflict-free b128
//   s_HG[64][64] dw : u16 rows 0..31 = h2[p][j], 32..63 = G[p][j], same swizzle
//   s_Y overlays s_A (dead after phase B): f32 y[32][33] then lap[32][33]
// Barriers: 4/pass for 32 points. A->s_A |b1| B reads s_A, C->s_HG |b2|
// D reads s_HG, writes s_Y(=s_A) |b3| E reads s_Y |b4(loop top)| next A.

__global__ __launch_bounds__(BLOCK, 4) void helmholtz_kernel(
    const float* __restrict__ x,      // [N,3]
    const float* __restrict__ omega,  // [16]
    const float* __restrict__ W1,     // [3,128]
    const float* __restrict__ b1,     // [128]
    const float* __restrict__ W2,     // [128,128]
    const float* __restrict__ b2,     // [128]
    const float* __restrict__ W3,     // [128,32]
    const float* __restrict__ b3,     // [32]
    float* __restrict__ out)
{
  __shared__ unsigned s_A[160 * 64];   // 40 KB
  __shared__ unsigned s_HG[64 * 64];   // 16 KB

  const int tid  = threadIdx.x;
  const int w    = tid >> 6;   // wave 0..7
  const int l    = tid & 63;
  const int col  = l & 15;
  const int quad = l >> 4;

  // ---- persistent per-thread registers ----
  // phase A: thread handles input-unit pair i0=2*i2, i1=2*i2+1 for pts w*4..w*4+3
  const int i2 = l;
  const float a0x = W1[2 * i2],     a0y = W1[128 + 2 * i2], a0z = W1[256 + 2 * i2];
  const float a1x = W1[2 * i2 + 1], a1y = W1[129 + 2 * i2], a1z = W1[257 + 2 * i2];
  const float bb0 = b1[2 * i2],     bb1 = b1[2 * i2 + 1];
  const float wsq0 = a0x * a0x + a0y * a0y + a0z * a0z;
  const float wsq1 = a1x * a1x + a1y * a1y + a1z * a1z;

  // phase B: wave w owns n-tile w (cols w*16+col). 16 VGPRs.
  half8 w2f[4];
  {
    const int n = w * 16 + col;
#pragma unroll
    for (int ks = 0; ks < 4; ks++) {
      half8 f;
#pragma unroll
      for (int j = 0; j < 8; j++)
        f[j] = (_Float16)W2[(ks * 32 + (quad << 3) + j) * 128 + n];
      w2f[ks] = f;
    }
  }
  // phase D: wave w owns tile (mtp=w>>1, ntp=w&1). 16 VGPRs.
  half8 w3f[4];
  {
    const int n = (w & 1) * 16 + col;
#pragma unroll
    for (int ks = 0; ks < 4; ks++) {
      half8 f;
#pragma unroll
      for (int j = 0; j < 8; j++)
        f[j] = (_Float16)W3[(ks * 32 + (quad << 3) + j) * 32 + n];
      w3f[ks] = f;
    }
  }

  // phase C: this thread's j-column
  const float b2v = b2[w * 16 + col];
  // phase E: thread owns (point p = tid>>4, channel cE = (tid&15)+1)
  const bool  activeE = (tid & 15) < 15;
  const int   cE = (tid & 15) + 1;
  float k2E = 0.0f, b3a = 0.0f, b3b = 0.0f;
  if (activeE) {
    float om = omega[cE] * (1.0f / CSND);
    k2E = om * om;
    b3a = b3[cE];
    b3b = b3[cE + 16];
  }

  float wsum = 0.0f;

  for (int blk = blockIdx.x; blk < NBLK; blk += gridDim.x) {
    const int pbase = blk * PB;
    __syncthreads();  // b4: prior pass's E reads of s_Y(=s_A) done

    // ---- phase A: layer 1 + 5 layer-2 input vectors -> s_A (f16, swizzled) ----
#pragma unroll
    for (int it = 0; it < 4; it++) {
      int p = w * 4 + it;
      const float* xp = x + (size_t)(pbase + p) * 3;
      float x0 = xp[0], x1 = xp[1], x2 = xp[2];
      float z0 = fmaf(x0, a0x, fmaf(x1, a0y, fmaf(x2, a0z, bb0)));
      float z1 = fmaf(x0, a1x, fmaf(x1, a1y, fmaf(x2, a1z, bb1)));
      float t0 = mytanh(z0), t1 = mytanh(z1);
      float s0 = 1.0f - t0 * t0, s1 = 1.0f - t1 * t1;
      unsigned u_h  = pack2(t0, t1);
      unsigned u_d0 = pack2(s0 * a0x, s1 * a1x);
      unsigned u_d1 = pack2(s0 * a0y, s1 * a1y);
      unsigned u_d2 = pack2(s0 * a0z, s1 * a1z);
      unsigned u_c  = pack2(-2.0f * t0 * s0 * wsq0, -2.0f * t1 * s1 * wsq1);
      int dcol = (((i2 >> 2) ^ (p & 15)) << 2) + (i2 & 3);
      s_A[(p)       * 64 + dcol] = u_h;
      s_A[(32 + p)  * 64 + dcol] = u_d0;
      s_A[(64 + p)  * 64 + dcol] = u_d1;
      s_A[(96 + p)  * 64 + dcol] = u_d2;
      s_A[(128 + p) * 64 + dcol] = u_c;
    }
    __syncthreads();  // b1

    // ---- phases B+C: two point-halves; acc[5] only (20 VGPRs) ----
    {
      _Float16* hg = (_Float16*)s_HG;
      const int j = w * 16 + col;
      const int chunkj = j >> 3;
#pragma unroll
      for (int ph = 0; ph < 2; ph++) {
        f32x4 acc[5];
#pragma unroll
        for (int v = 0; v < 5; v++) acc[v] = (f32x4){0.0f, 0.0f, 0.0f, 0.0f};
#pragma unroll
        for (int v = 0; v < 5; v++) {
          int m = v * 32 + ph * 16 + col;   // row&15 = col
#pragma unroll
          for (int ks = 0; ks < 4; ks++) {
            int c = (ks * 4 + quad) ^ col;
            half8 af = *(const half8*)&s_A[m * 64 + (c << 2)];
            acc[v] = __builtin_amdgcn_mfma_f32_16x16x32_f16(af, w2f[ks], acc[v], 0, 0, 0);
          }
        }
        // layer-2 elementwise for points p = ph*16 + quad*4 + r, column j
#pragma unroll
        for (int r = 0; r < 4; r++) {
          int p = ph * 16 + quad * 4 + r;
          float z2 = acc[0][r] + b2v;
          float d0 = acc[1][r], d1 = acc[2][r], d2 = acc[3][r];
          float Av = acc[4][r];
          float t2 = mytanh(z2);
          float s2 = 1.0f - t2 * t2;
          float g  = s2 * (Av - 2.0f * t2 * (d0 * d0 + d1 * d1 + d2 * d2));
          int base = ((chunkj ^ (p & 15)) << 3) + (j & 7);
          hg[p * 128 + base]        = (_Float16)t2;   // h2 rows 0..31
          hg[(32 + p) * 128 + base] = (_Float16)g;    // G  rows 32..63
        }
      }
    }
    __syncthreads();  // b2

    // ---- phase D: [64 x 128] x [128 x 32]; one 16x16 tile per wave ----
    {
      const int mtp = w >> 1, ntp = w & 1;
      const int mrow = mtp * 16 + col;
      f32x4 dacc = (f32x4){0.0f, 0.0f, 0.0f, 0.0f};
#pragma unroll
      for (int ks = 0; ks < 4; ks++) {
        int ca = (ks * 4 + quad) ^ col;
        half8 af = *(const half8*)&s_HG[mrow * 64 + (ca << 2)];
        dacc = __builtin_amdgcn_mfma_f32_16x16x32_f16(af, w3f[ks], dacc, 0, 0, 0);
      }
      float* s_Yf = (float*)s_A;            // overlay: y[32][33], lap at +1056
      const int ybase = (mtp >= 2 ? 1056 : 0) + ((mtp & 1) * 16) * 33 + ntp * 16 + col;
#pragma unroll
      for (int r = 0; r < 4; r++)
        s_Yf[ybase + (quad * 4 + r) * 33] = dacc[r];
    }
    __syncthreads();  // b3

    // ---- phase E: residual ----
    if (activeE) {
      const float* s_Yf = (const float*)s_A;
      int p = tid >> 4;
      float yre = s_Yf[p * 33 + cE] + b3a;
      float yim = s_Yf[p * 33 + cE + 16] + b3b;
      float lre = s_Yf[1056 + p * 33 + cE];
      float lim = s_Yf[1056 + p * 33 + cE + 16];
      float re = fmaf(k2E, yre, lre);
      float im = fmaf(k2E, yim, lim);
      wsum += re * re + im * im;
    }
  }

  // ---- final: wave reduce, one atomic per wave ----
#pragma unroll
  for (int off = 32; off > 0; off >>= 1)
    wsum += __shfl_down(wsum, off, 64);
  if (l == 0)
    atomicAdd(out, wsum * (1.0f / ((float)NPTS * (float)(FCH - 1))));
}

extern "C" void kernel_launch(void* const* d_in, const int* in_sizes, int n_in,
                              void* d_out, int out_size, void* d_ws, size_t ws_size,
                              hipStream_t stream) {
  const float* x     = (const float*)d_in[0];
  const float* omega = (const float*)d_in[1];
  const float* W1    = (const float*)d_in[2];
  const float* b1    = (const float*)d_in[3];
  const float* W2    = (const float*)d_in[4];
  const float* b2    = (const float*)d_in[5];
  const float* W3    = (const float*)d_in[6];
  const float* b3    = (const float*)d_in[7];
  float* out = (float*)d_out;

  (void)hipMemsetAsync(out, 0, sizeof(float), stream);
  helmholtz_kernel<<<GRID, BLOCK, 0, stream>>>(x, omega, W1, b1, W2, b2, W3, b3, out);
}

// Round 6
// 129.150 us; speedup vs baseline: 1.1812x; 1.1312x over previous
//
#include <hip/hip_runtime.h>
#include <math.h>

#ifndef __has_builtin
#define __has_builtin(x) 0
#endif

#define NPTS   131072
#define FCH    16
#define CSND   343.0f
#define PB     16           // points per workgroup pass
#define BLOCK  256          // 4 waves
#define GRID   768          // 3 WG/CU * 256 CUs, persistent
#define NBLK   (NPTS / PB)  // 8192

typedef _Float16 half8 __attribute__((ext_vector_type(8)));
typedef _Float16 half2v __attribute__((ext_vector_type(2)));
typedef float    f32x4 __attribute__((ext_vector_type(4)));

static __device__ __forceinline__ unsigned pack2(float a, float b) {
#if __has_builtin(__builtin_amdgcn_cvt_pkrtz)
  return __builtin_bit_cast(unsigned, __builtin_amdgcn_cvt_pkrtz(a, b));
#else
  half2v v; v[0] = (_Float16)a; v[1] = (_Float16)b;
  return __builtin_bit_cast(unsigned, v);
#endif
}

static __device__ __forceinline__ float mytanh(float x) {
  float ax = fabsf(x);
  float e  = __expf(-2.0f * ax);
  float r  = (1.0f - e) * __builtin_amdgcn_rcpf(1.0f + e);
  return copysignf(r, x);
}

// LDS (28 KB -> LDS-unbound; occupancy set by launch_bounds(256,3) = 3 WG/CU):
//   s_A[80][64] dw : A f16, rows v*16+p (v=0..4: h1,d0,d1,d2,c1),
//                    chunk c of 8 k-vals at (c ^ (row&15)) -> conflict-free b128
//   s_HG[32][64] dw: u16 rows 0..15 = h2[p][j], 16..31 = G[p][j], same swizzle
// Barriers: 2 per pass.
//   A -> s_A  |b1|  B reads s_A, C -> s_HG  |b2|  waves 0,1: D reads s_HG,
//   residual combined IN-LANE (wave0: real channels -> re^2; wave1: imag -> im^2),
//   then loop. Cross-pass hazards: A(i+1) vs B(i) spans b2(i); C(i+1) vs D(i)
//   spans b1(i+1) since waves 0,1 pass it only after finishing D(i).

__global__ __launch_bounds__(BLOCK, 3) void helmholtz_kernel(
    const float* __restrict__ x,      // [N,3]
    const float* __restrict__ omega,  // [16]
    const float* __restrict__ W1,     // [3,128]
    const float* __restrict__ b1,     // [128]
    const float* __restrict__ W2,     // [128,128]
    const float* __restrict__ b2,     // [128]
    const float* __restrict__ W3,     // [128,32]
    const float* __restrict__ b3,     // [32]
    float* __restrict__ out)
{
  __shared__ unsigned s_A[80 * 64];    // 20 KB
  __shared__ unsigned s_HG[32 * 64];   //  8 KB

  const int tid  = threadIdx.x;
  const int w    = tid >> 6;   // wave 0..3
  const int l    = tid & 63;
  const int col  = l & 15;
  const int quad = l >> 4;

  // ---- persistent per-thread registers ----
  // phase A: thread handles input-unit pair i0=2*i2, i1=2*i2+1
  const int i2 = l;
  const float a0x = W1[2 * i2],     a0y = W1[128 + 2 * i2], a0z = W1[256 + 2 * i2];
  const float a1x = W1[2 * i2 + 1], a1y = W1[129 + 2 * i2], a1z = W1[257 + 2 * i2];
  const float bb0 = b1[2 * i2],     bb1 = b1[2 * i2 + 1];
  const float wsq0 = a0x * a0x + a0y * a0y + a0z * a0z;
  const float wsq1 = a1x * a1x + a1y * a1y + a1z * a1z;

  // phase B: wave w owns n-tiles 2w, 2w+1 (32 VGPRs of W2^T fragments)
  half8 w2f[2][4];
#pragma unroll
  for (int ntl = 0; ntl < 2; ntl++) {
    const int n = (2 * w + ntl) * 16 + col;
#pragma unroll
    for (int ks = 0; ks < 4; ks++) {
      half8 f;
#pragma unroll
      for (int j = 0; j < 8; j++)
        f[j] = (_Float16)W2[(ks * 32 + (quad << 3) + j) * 128 + n];
      w2f[ntl][ks] = f;
    }
  }
  // phase D: wave 0 -> real cols (0..15), wave 1 -> imag cols (16..31)
  half8 w3f[4];
  {
    const int n = (w & 1) * 16 + col;
#pragma unroll
    for (int ks = 0; ks < 4; ks++) {
      half8 f;
#pragma unroll
      for (int j = 0; j < 8; j++)
        f[j] = (_Float16)W3[(ks * 32 + (quad << 3) + j) * 32 + n];
      w3f[ks] = f;
    }
  }

  // phase C biases
  const float b2r0 = b2[2 * w * 16 + col];
  const float b2r1 = b2[(2 * w + 1) * 16 + col];
  // phase D/E: channel = col (freq index), k2 shared by re/im waves
  float k2v = 0.0f;
  if (col >= 1) {
    float om = omega[col] * (1.0f / CSND);
    k2v = om * om;
  }
  const float b3v = b3[(w & 1) * 16 + col];

  float wsum = 0.0f;

  for (int blk = blockIdx.x; blk < NBLK; blk += gridDim.x) {
    const int pbase = blk * PB;

    // ---- phase A: layer 1 + 5 layer-2 input vectors -> s_A (f16, swizzled) ----
#pragma unroll
    for (int it = 0; it < 4; it++) {
      int p = w * 4 + it;
      const float* xp = x + (size_t)(pbase + p) * 3;
      float x0 = xp[0], x1 = xp[1], x2 = xp[2];
      float z0 = fmaf(x0, a0x, fmaf(x1, a0y, fmaf(x2, a0z, bb0)));
      float z1 = fmaf(x0, a1x, fmaf(x1, a1y, fmaf(x2, a1z, bb1)));
      float t0 = mytanh(z0), t1 = mytanh(z1);
      float s0 = 1.0f - t0 * t0, s1 = 1.0f - t1 * t1;
      unsigned u_h  = pack2(t0, t1);
      unsigned u_d0 = pack2(s0 * a0x, s1 * a1x);
      unsigned u_d1 = pack2(s0 * a0y, s1 * a1y);
      unsigned u_d2 = pack2(s0 * a0z, s1 * a1z);
      unsigned u_c  = pack2(-2.0f * t0 * s0 * wsq0, -2.0f * t1 * s1 * wsq1);
      int dcol = (((i2 >> 2) ^ p) << 2) + (i2 & 3);
      s_A[(p)      * 64 + dcol] = u_h;
      s_A[(16 + p) * 64 + dcol] = u_d0;
      s_A[(32 + p) * 64 + dcol] = u_d1;
      s_A[(48 + p) * 64 + dcol] = u_d2;
      s_A[(64 + p) * 64 + dcol] = u_c;
    }
    __syncthreads();  // b1

    // ---- phase B: [80 x 128] x [128 x 128]; wave w covers n-tiles 2w,2w+1 ----
    f32x4 acc[5][2];
#pragma unroll
    for (int mt = 0; mt < 5; mt++)
#pragma unroll
      for (int ntl = 0; ntl < 2; ntl++)
        acc[mt][ntl] = (f32x4){0.0f, 0.0f, 0.0f, 0.0f};

#pragma unroll
    for (int mt = 0; mt < 5; mt++) {
      int m = mt * 16 + col;
#pragma unroll
      for (int ks = 0; ks < 4; ks++) {
        int c = (ks * 4 + quad) ^ col;
        half8 af = *(const half8*)&s_A[m * 64 + (c << 2)];
        acc[mt][0] = __builtin_amdgcn_mfma_f32_16x16x32_f16(af, w2f[0][ks], acc[mt][0], 0, 0, 0);
        acc[mt][1] = __builtin_amdgcn_mfma_f32_16x16x32_f16(af, w2f[1][ks], acc[mt][1], 0, 0, 0);
      }
    }

    // ---- phase C: layer-2 elementwise in registers; write h2/G f16 -> s_HG ----
    {
      _Float16* hg = (_Float16*)s_HG;
#pragma unroll
      for (int ntl = 0; ntl < 2; ntl++) {
        int j = (2 * w + ntl) * 16 + col;
        int chunkj = j >> 3;
        float b2v = ntl ? b2r1 : b2r0;
#pragma unroll
        for (int r = 0; r < 4; r++) {
          int p = quad * 4 + r;
          float z2 = acc[0][ntl][r] + b2v;
          float d0 = acc[1][ntl][r], d1 = acc[2][ntl][r], d2 = acc[3][ntl][r];
          float Av = acc[4][ntl][r];
          float t2 = mytanh(z2);
          float s2 = 1.0f - t2 * t2;
          float g  = s2 * (Av - 2.0f * t2 * (d0 * d0 + d1 * d1 + d2 * d2));
          int base = ((chunkj ^ p) << 3) + (j & 7);
          hg[p * 128 + base]        = (_Float16)t2;   // h2 rows 0..15
          hg[(16 + p) * 128 + base] = (_Float16)g;    // G  rows 16..31
        }
      }
    }
    __syncthreads();  // b2

    // ---- phase D+E (waves 0,1 only): y & lap tiles in-lane, residual in regs ----
    if (w < 2) {
      f32x4 dy = (f32x4){0.0f, 0.0f, 0.0f, 0.0f};
      f32x4 dl = (f32x4){0.0f, 0.0f, 0.0f, 0.0f};
#pragma unroll
      for (int ks = 0; ks < 4; ks++) {
        int ca = (ks * 4 + quad) ^ col;
        half8 afy = *(const half8*)&s_HG[(col)      * 64 + (ca << 2)];  // h2 rows
        half8 afl = *(const half8*)&s_HG[(16 + col) * 64 + (ca << 2)];  // G rows
        dy = __builtin_amdgcn_mfma_f32_16x16x32_f16(afy, w3f[ks], dy, 0, 0, 0);
        dl = __builtin_amdgcn_mfma_f32_16x16x32_f16(afl, w3f[ks], dl, 0, 0, 0);
      }
      // lane (col,quad) reg r: point p=quad*4+r, channel col (wave0: re, wave1: im)
      if (col >= 1) {
#pragma unroll
        for (int r = 0; r < 4; r++) {
          float yv  = dy[r] + b3v;
          float res = fmaf(k2v, yv, dl[r]);
          wsum += res * res;
        }
      }
    }
    // no further barrier: next A writes only s_A (B-reads ended before b2);
    // next C writes s_HG only after b1(i+1), which waves 0,1 reach after D(i).
  }

  // ---- final: wave reduce, one atomic per wave ----
#pragma unroll
  for (int off = 32; off > 0; off >>= 1)
    wsum += __shfl_down(wsum, off, 64);
  if (l == 0)
    atomicAdd(out, wsum * (1.0f / ((float)NPTS * (float)(FCH - 1))));
}

extern "C" void kernel_launch(void* const* d_in, const int* in_sizes, int n_in,
                              void* d_out, int out_size, void* d_ws, size_t ws_size,
                              hipStream_t stream) {
  const float* x     = (const float*)d_in[0];
  const float* omega = (const float*)d_in[1];
  const float* W1    = (const float*)d_in[2];
  const float* b1    = (const float*)d_in[3];
  const float* W2    = (const float*)d_in[4];
  const float* b2    = (const float*)d_in[5];
  const float* W3    = (const float*)d_in[6];
  const float* b3    = (const float*)d_in[7];
  float* out = (float*)d_out;

  (void)hipMemsetAsync(out, 0, sizeof(float), stream);
  helmholtz_kernel<<<GRID, BLOCK, 0, stream>>>(x, omega, W1, b1, W2, b2, W3, b3, out);
}

// Round 7
// 123.893 us; speedup vs baseline: 1.2313x; 1.0424x over previous
//
#include <hip/hip_runtime.h>
#include <math.h>

#ifndef __has_builtin
#define __has_builtin(x) 0
#endif

#define NPTS   131072
#define FCH    16
#define CSND   343.0f
#define PB     16           // points per pass
#define BLOCK  256          // 4 waves
#define GRID   512          // 2 WG/CU * 256 CUs, persistent
#define NBLK   (NPTS / PB)  // 8192

typedef _Float16 half8 __attribute__((ext_vector_type(8)));
typedef _Float16 half2v __attribute__((ext_vector_type(2)));
typedef float    f32x4 __attribute__((ext_vector_type(4)));

static __device__ __forceinline__ unsigned pack2(float a, float b) {
#if __has_builtin(__builtin_amdgcn_cvt_pkrtz)
  return __builtin_bit_cast(unsigned, __builtin_amdgcn_cvt_pkrtz(a, b));
#else
  half2v v; v[0] = (_Float16)a; v[1] = (_Float16)b;
  return __builtin_bit_cast(unsigned, v);
#endif
}

static __device__ __forceinline__ float mytanh(float x) {
  float ax = fabsf(x);
  float e  = __expf(-2.0f * ax);
  float r  = (1.0f - e) * __builtin_amdgcn_rcpf(1.0f + e);
  return copysignf(r, x);
}

// Software-pipelined, double-buffered (56 KB LDS -> 2 WG/CU):
//   s_A[2][80][64] dw : A f16, rows v*16+p, chunk c at (c ^ (row&15))
//   s_HG[2][32][64] dw: u16 rows 0..15 = h2, 16..31 = G, same swizzle
// Per-pass schedule (ONE barrier):
//   A(i+1)->bufA[p^1]  ||  B(i) reads bufA[p], C(i)->HG[p]   | bar |
//   waves 0,1: D(i) reads HG[p], residual in-lane.
// A(i+1) is pure VALU, B(i) is LDS+MFMA -> independent streams interleave.
// Hazards: A(i+1) vs B(i+1) reads span bar(i); A(i+1) writes bufA[p] only
// where B(i) read bufA[p] BEFORE bar(i) in the same iteration order; C(i+2)
// (after bar(i+1)) vs D(i) (before any wave reaches bar(i+1)). All safe.

__global__ __launch_bounds__(BLOCK, 2) void helmholtz_kernel(
    const float* __restrict__ x,      // [N,3]
    const float* __restrict__ omega,  // [16]
    const float* __restrict__ W1,     // [3,128]
    const float* __restrict__ b1,     // [128]
    const float* __restrict__ W2,     // [128,128]
    const float* __restrict__ b2,     // [128]
    const float* __restrict__ W3,     // [128,32]
    const float* __restrict__ b3,     // [32]
    float* __restrict__ out)
{
  __shared__ unsigned s_A[2][80 * 64];    // 40 KB
  __shared__ unsigned s_HG[2][32 * 64];   // 16 KB

  const int tid  = threadIdx.x;
  const int w    = tid >> 6;   // wave 0..3
  const int l    = tid & 63;
  const int col  = l & 15;
  const int quad = l >> 4;

  // ---- persistent per-thread registers ----
  const int i2 = l;
  const float a0x = W1[2 * i2],     a0y = W1[128 + 2 * i2], a0z = W1[256 + 2 * i2];
  const float a1x = W1[2 * i2 + 1], a1y = W1[129 + 2 * i2], a1z = W1[257 + 2 * i2];
  const float bb0 = b1[2 * i2],     bb1 = b1[2 * i2 + 1];
  const float wsq0 = a0x * a0x + a0y * a0y + a0z * a0z;
  const float wsq1 = a1x * a1x + a1y * a1y + a1z * a1z;

  // W2^T fragments for n-tiles 2w, 2w+1 (32 VGPRs)
  half8 w2f[2][4];
#pragma unroll
  for (int ntl = 0; ntl < 2; ntl++) {
    const int n = (2 * w + ntl) * 16 + col;
#pragma unroll
    for (int ks = 0; ks < 4; ks++) {
      half8 f;
#pragma unroll
      for (int j = 0; j < 8; j++)
        f[j] = (_Float16)W2[(ks * 32 + (quad << 3) + j) * 128 + n];
      w2f[ntl][ks] = f;
    }
  }
  // W3^T fragment: wave 0 -> real cols, wave 1 -> imag cols (16 VGPRs)
  half8 w3f[4];
  {
    const int n = (w & 1) * 16 + col;
#pragma unroll
    for (int ks = 0; ks < 4; ks++) {
      half8 f;
#pragma unroll
      for (int j = 0; j < 8; j++)
        f[j] = (_Float16)W3[(ks * 32 + (quad << 3) + j) * 32 + n];
      w3f[ks] = f;
    }
  }

  const float b2r0 = b2[2 * w * 16 + col];
  const float b2r1 = b2[(2 * w + 1) * 16 + col];
  float k2v = 0.0f;
  if (col >= 1) {
    float om = omega[col] * (1.0f / CSND);
    k2v = om * om;
  }
  const float b3v = b3[(w & 1) * 16 + col];

  float wsum = 0.0f;

  // ---- phase A as a reusable lambda ----
  auto phaseA = [&](int blk, int buf) {
    const int pbase = blk * PB;
    unsigned* sA = s_A[buf];
#pragma unroll
    for (int it = 0; it < 4; it++) {
      int p = w * 4 + it;
      const float* xp = x + (size_t)(pbase + p) * 3;
      float x0 = xp[0], x1 = xp[1], x2 = xp[2];
      float z0 = fmaf(x0, a0x, fmaf(x1, a0y, fmaf(x2, a0z, bb0)));
      float z1 = fmaf(x0, a1x, fmaf(x1, a1y, fmaf(x2, a1z, bb1)));
      float t0 = mytanh(z0), t1 = mytanh(z1);
      float s0 = 1.0f - t0 * t0, s1 = 1.0f - t1 * t1;
      unsigned u_h  = pack2(t0, t1);
      unsigned u_d0 = pack2(s0 * a0x, s1 * a1x);
      unsigned u_d1 = pack2(s0 * a0y, s1 * a1y);
      unsigned u_d2 = pack2(s0 * a0z, s1 * a1z);
      unsigned u_c  = pack2(-2.0f * t0 * s0 * wsq0, -2.0f * t1 * s1 * wsq1);
      int dcol = (((i2 >> 2) ^ p) << 2) + (i2 & 3);
      sA[(p)      * 64 + dcol] = u_h;
      sA[(16 + p) * 64 + dcol] = u_d0;
      sA[(32 + p) * 64 + dcol] = u_d1;
      sA[(48 + p) * 64 + dcol] = u_d2;
      sA[(64 + p) * 64 + dcol] = u_c;
    }
  };

  // ---- prologue ----
  phaseA(blockIdx.x, 0);
  __syncthreads();

  int parity = 0;
  for (int blk = blockIdx.x; blk < NBLK; blk += gridDim.x, parity ^= 1) {
    // ---- A(i+1): pure VALU, independent of B(i) below ----
    int nblk = blk + (int)gridDim.x;
    if (nblk < NBLK) phaseA(nblk, parity ^ 1);

    // ---- B(i): [80x128]x[128x128] from s_A[parity]; wave w n-tiles 2w,2w+1 ----
    const unsigned* sA = s_A[parity];
    f32x4 acc[5][2];
#pragma unroll
    for (int mt = 0; mt < 5; mt++)
#pragma unroll
      for (int ntl = 0; ntl < 2; ntl++)
        acc[mt][ntl] = (f32x4){0.0f, 0.0f, 0.0f, 0.0f};

#pragma unroll
    for (int mt = 0; mt < 5; mt++) {
      int m = mt * 16 + col;
#pragma unroll
      for (int ks = 0; ks < 4; ks++) {
        int c = (ks * 4 + quad) ^ col;
        half8 af = *(const half8*)&sA[m * 64 + (c << 2)];
        acc[mt][0] = __builtin_amdgcn_mfma_f32_16x16x32_f16(af, w2f[0][ks], acc[mt][0], 0, 0, 0);
        acc[mt][1] = __builtin_amdgcn_mfma_f32_16x16x32_f16(af, w2f[1][ks], acc[mt][1], 0, 0, 0);
      }
    }

    // ---- C(i): layer-2 elementwise -> s_HG[parity] ----
    {
      _Float16* hg = (_Float16*)s_HG[parity];
#pragma unroll
      for (int ntl = 0; ntl < 2; ntl++) {
        int j = (2 * w + ntl) * 16 + col;
        int chunkj = j >> 3;
        float b2v = ntl ? b2r1 : b2r0;
#pragma unroll
        for (int r = 0; r < 4; r++) {
          int p = quad * 4 + r;
          float z2 = acc[0][ntl][r] + b2v;
          float d0 = acc[1][ntl][r], d1 = acc[2][ntl][r], d2 = acc[3][ntl][r];
          float Av = acc[4][ntl][r];
          float t2 = mytanh(z2);
          float s2 = 1.0f - t2 * t2;
          float g  = s2 * (Av - 2.0f * t2 * (d0 * d0 + d1 * d1 + d2 * d2));
          int base = ((chunkj ^ p) << 3) + (j & 7);
          hg[p * 128 + base]        = (_Float16)t2;   // h2 rows 0..15
          hg[(16 + p) * 128 + base] = (_Float16)g;    // G  rows 16..31
        }
      }
    }
    __syncthreads();  // the ONE barrier per pass

    // ---- D+E (waves 0,1): y & lap tiles in-lane, residual in regs ----
    if (w < 2) {
      const unsigned* hgb = s_HG[parity];
      f32x4 dy = (f32x4){0.0f, 0.0f, 0.0f, 0.0f};
      f32x4 dl = (f32x4){0.0f, 0.0f, 0.0f, 0.0f};
#pragma unroll
      for (int ks = 0; ks < 4; ks++) {
        int ca = (ks * 4 + quad) ^ col;
        half8 afy = *(const half8*)&hgb[(col)      * 64 + (ca << 2)];
        half8 afl = *(const half8*)&hgb[(16 + col) * 64 + (ca << 2)];
        dy = __builtin_amdgcn_mfma_f32_16x16x32_f16(afy, w3f[ks], dy, 0, 0, 0);
        dl = __builtin_amdgcn_mfma_f32_16x16x32_f16(afl, w3f[ks], dl, 0, 0, 0);
      }
      if (col >= 1) {
#pragma unroll
        for (int r = 0; r < 4; r++) {
          float yv  = dy[r] + b3v;
          float res = fmaf(k2v, yv, dl[r]);
          wsum += res * res;
        }
      }
    }
  }

  // ---- final: wave reduce, one atomic per wave ----
#pragma unroll
  for (int off = 32; off > 0; off >>= 1)
    wsum += __shfl_down(wsum, off, 64);
  if (l == 0)
    atomicAdd(out, wsum * (1.0f / ((float)NPTS * (float)(FCH - 1))));
}

extern "C" void kernel_launch(void* const* d_in, const int* in_sizes, int n_in,
                              void* d_out, int out_size, void* d_ws, size_t ws_size,
                              hipStream_t stream) {
  const float* x     = (const float*)d_in[0];
  const float* omega = (const float*)d_in[1];
  const float* W1    = (const float*)d_in[2];
  const float* b1    = (const float*)d_in[3];
  const float* W2    = (const float*)d_in[4];
  const float* b2    = (const float*)d_in[5];
  const float* W3    = (const float*)d_in[6];
  const float* b3    = (const float*)d_in[7];
  float* out = (float*)d_out;

  (void)hipMemsetAsync(out, 0, sizeof(float), stream);
  helmholtz_kernel<<<GRID, BLOCK, 0, stream>>>(x, omega, W1, b1, W2, b2, W3, b3, out);
}

// Round 8
// 121.354 us; speedup vs baseline: 1.2571x; 1.0209x over previous
//
#include <hip/hip_runtime.h>
#include <math.h>

#ifndef __has_builtin
#define __has_builtin(x) 0
#endif

#define NPTS   131072
#define FCH    16
#define CSND   343.0f
#define PB     16           // points per pass
#define BLOCK  256          // 4 waves
#define GRID   512          // 2 WG/CU * 256 CUs, persistent
#define NBLK   (NPTS / PB)  // 8192

typedef _Float16 half8 __attribute__((ext_vector_type(8)));
typedef _Float16 half2v __attribute__((ext_vector_type(2)));
typedef float    f32x4 __attribute__((ext_vector_type(4)));

static __device__ __forceinline__ unsigned pack2(float a, float b) {
#if __has_builtin(__builtin_amdgcn_cvt_pkrtz)
  return __builtin_bit_cast(unsigned, __builtin_amdgcn_cvt_pkrtz(a, b));
#else
  half2v v; v[0] = (_Float16)a; v[1] = (_Float16)b;
  return __builtin_bit_cast(unsigned, v);
#endif
}

// tanh(x) = 1 - 2/(e^{2x}+1): 1 mul + 1 v_exp + 1 add + 1 rcp + 1 fma.
// Monotone-correct limits: x->+inf: e=inf, rcp=0, t=1; x->-inf: e=0, t=-1.
static __device__ __forceinline__ float mytanh(float x) {
#if __has_builtin(__builtin_amdgcn_exp2f)
  float e = __builtin_amdgcn_exp2f(2.885390082f * x);   // 2*log2(e)*x
#else
  float e = __expf(2.0f * x);
#endif
  return fmaf(-2.0f, __builtin_amdgcn_rcpf(e + 1.0f), 1.0f);
}

// Software-pipelined, double-buffered (56 KB LDS -> 2 WG/CU):
//   s_A[2][80][64] dw : A f16, rows v*16+p, chunk c (8 units) at (c ^ p)
//   s_HG[2][32][64] dw: u16 rows 0..15 = h2, 16..31 = G, same swizzle
// Per-pass schedule (ONE barrier, D moved pre-barrier):
//   waves 0,1: D(i-1) from HG[par^1], residual in-lane
//   all: A(i+1)->bufA[par^1]  ||  B(i) reads bufA[par], C(i)->HG[par] | bar |
// Hazards: D(i-1) vs C(i+1) writes HG[par^1] only after bar(i);
// A(i+1) vs B(i) same-iteration order + bar; B(i+1) reads after bar(i). Safe.

__global__ __launch_bounds__(BLOCK, 2) void helmholtz_kernel(
    const float* __restrict__ x,      // [N,3]
    const float* __restrict__ omega,  // [16]
    const float* __restrict__ W1,     // [3,128]
    const float* __restrict__ b1,     // [128]
    const float* __restrict__ W2,     // [128,128]
    const float* __restrict__ b2,     // [128]
    const float* __restrict__ W3,     // [128,32]
    const float* __restrict__ b3,     // [32]
    float* __restrict__ out)
{
  __shared__ unsigned s_A[2][80 * 64];    // 40 KB
  __shared__ unsigned s_HG[2][32 * 64];   // 16 KB

  const int tid  = threadIdx.x;
  const int w    = tid >> 6;   // wave 0..3
  const int l    = tid & 63;
  const int col  = l & 15;
  const int quad = l >> 4;

  // ---- phase A task: point pA = tid>>4 (wave w owns 4w..4w+3), units 8g..8g+7 ----
  const int pA = tid >> 4;
  const int g  = tid & 15;
  float wx[8], wy[8], wz[8], bB[8], wq[8];
#pragma unroll
  for (int u = 0; u < 8; u++) {
    int unit = 8 * g + u;
    wx[u] = W1[unit]; wy[u] = W1[128 + unit]; wz[u] = W1[256 + unit];
    bB[u] = b1[unit];
    wq[u] = wx[u] * wx[u] + wy[u] * wy[u] + wz[u] * wz[u];
  }

  // W2^T fragments for n-tiles 2w, 2w+1 (32 VGPRs)
  half8 w2f[2][4];
#pragma unroll
  for (int ntl = 0; ntl < 2; ntl++) {
    const int n = (2 * w + ntl) * 16 + col;
#pragma unroll
    for (int ks = 0; ks < 4; ks++) {
      half8 f;
#pragma unroll
      for (int j = 0; j < 8; j++)
        f[j] = (_Float16)W2[(ks * 32 + (quad << 3) + j) * 128 + n];
      w2f[ntl][ks] = f;
    }
  }
  // W3^T fragment: wave 0 -> real cols, wave 1 -> imag cols (16 VGPRs)
  half8 w3f[4];
  {
    const int n = (w & 1) * 16 + col;
#pragma unroll
    for (int ks = 0; ks < 4; ks++) {
      half8 f;
#pragma unroll
      for (int j = 0; j < 8; j++)
        f[j] = (_Float16)W3[(ks * 32 + (quad << 3) + j) * 32 + n];
      w3f[ks] = f;
    }
  }

  const float b2r0 = b2[2 * w * 16 + col];
  const float b2r1 = b2[(2 * w + 1) * 16 + col];
  float k2v = 0.0f;
  if (col >= 1) {
    float om = omega[col] * (1.0f / CSND);
    k2v = om * om;
  }
  const float b3v = b3[(w & 1) * 16 + col];

  float wsum = 0.0f;

  // ---- phase A: one point, 8 units, 5 ds_write_b128 ----
  auto phaseA = [&](int blk, int buf) {
    const float* xp = x + (size_t)(blk * PB + pA) * 3;
    float x0 = xp[0], x1 = xp[1], x2 = xp[2];
    float t[8], s[8];
#pragma unroll
    for (int u = 0; u < 8; u++) {
      float z = fmaf(x0, wx[u], fmaf(x1, wy[u], fmaf(x2, wz[u], bB[u])));
      t[u] = mytanh(z);
      s[u] = 1.0f - t[u] * t[u];
    }
    unsigned* sA = s_A[buf];
    const int base = (g ^ pA) << 2;
    uint4 q;
    q = make_uint4(pack2(t[0], t[1]), pack2(t[2], t[3]),
                   pack2(t[4], t[5]), pack2(t[6], t[7]));
    *(uint4*)&sA[(pA)      * 64 + base] = q;
    q = make_uint4(pack2(s[0] * wx[0], s[1] * wx[1]), pack2(s[2] * wx[2], s[3] * wx[3]),
                   pack2(s[4] * wx[4], s[5] * wx[5]), pack2(s[6] * wx[6], s[7] * wx[7]));
    *(uint4*)&sA[(16 + pA) * 64 + base] = q;
    q = make_uint4(pack2(s[0] * wy[0], s[1] * wy[1]), pack2(s[2] * wy[2], s[3] * wy[3]),
                   pack2(s[4] * wy[4], s[5] * wy[5]), pack2(s[6] * wy[6], s[7] * wy[7]));
    *(uint4*)&sA[(32 + pA) * 64 + base] = q;
    q = make_uint4(pack2(s[0] * wz[0], s[1] * wz[1]), pack2(s[2] * wz[2], s[3] * wz[3]),
                   pack2(s[4] * wz[4], s[5] * wz[5]), pack2(s[6] * wz[6], s[7] * wz[7]));
    *(uint4*)&sA[(48 + pA) * 64 + base] = q;
    float c[8];
#pragma unroll
    for (int u = 0; u < 8; u++) c[u] = -2.0f * t[u] * s[u] * wq[u];
    q = make_uint4(pack2(c[0], c[1]), pack2(c[2], c[3]),
                   pack2(c[4], c[5]), pack2(c[6], c[7]));
    *(uint4*)&sA[(64 + pA) * 64 + base] = q;
  };

  // ---- phase D+E (waves 0,1): y & lap tiles in-lane, residual in regs ----
  auto phaseDE = [&](int buf) {
    const unsigned* hgb = s_HG[buf];
    f32x4 dy = (f32x4){0.0f, 0.0f, 0.0f, 0.0f};
    f32x4 dl = (f32x4){0.0f, 0.0f, 0.0f, 0.0f};
#pragma unroll
    for (int ks = 0; ks < 4; ks++) {
      int ca = (ks * 4 + quad) ^ col;
      half8 afy = *(const half8*)&hgb[(col)      * 64 + (ca << 2)];
      half8 afl = *(const half8*)&hgb[(16 + col) * 64 + (ca << 2)];
      dy = __builtin_amdgcn_mfma_f32_16x16x32_f16(afy, w3f[ks], dy, 0, 0, 0);
      dl = __builtin_amdgcn_mfma_f32_16x16x32_f16(afl, w3f[ks], dl, 0, 0, 0);
    }
    if (col >= 1) {
#pragma unroll
      for (int r = 0; r < 4; r++) {
        float yv  = dy[r] + b3v;
        float res = fmaf(k2v, yv, dl[r]);
        wsum += res * res;
      }
    }
  };

  // ---- prologue ----
  phaseA(blockIdx.x, 0);
  __syncthreads();

  int parity = 0;
  for (int blk = blockIdx.x; blk < NBLK; blk += gridDim.x, parity ^= 1) {
    // ---- D(i-1)+E(i-1): waves 0,1; reads HG[parity^1] (pre-barrier region) ----
    if (w < 2 && blk != (int)blockIdx.x) phaseDE(parity ^ 1);

    // ---- A(i+1): pure VALU, independent of B(i) below ----
    int nblk = blk + (int)gridDim.x;
    if (nblk < NBLK) phaseA(nblk, parity ^ 1);

    // ---- B(i): [80x128]x[128x128] from s_A[parity]; wave w n-tiles 2w,2w+1 ----
    const unsigned* sA = s_A[parity];
    f32x4 acc[5][2];
#pragma unroll
    for (int mt = 0; mt < 5; mt++)
#pragma unroll
      for (int ntl = 0; ntl < 2; ntl++)
        acc[mt][ntl] = (f32x4){0.0f, 0.0f, 0.0f, 0.0f};

#pragma unroll
    for (int mt = 0; mt < 5; mt++) {
      int m = mt * 16 + col;
#pragma unroll
      for (int ks = 0; ks < 4; ks++) {
        int c = (ks * 4 + quad) ^ col;
        half8 af = *(const half8*)&sA[m * 64 + (c << 2)];
        acc[mt][0] = __builtin_amdgcn_mfma_f32_16x16x32_f16(af, w2f[0][ks], acc[mt][0], 0, 0, 0);
        acc[mt][1] = __builtin_amdgcn_mfma_f32_16x16x32_f16(af, w2f[1][ks], acc[mt][1], 0, 0, 0);
      }
    }

    // ---- C(i): layer-2 elementwise -> s_HG[parity] ----
    {
      _Float16* hg = (_Float16*)s_HG[parity];
#pragma unroll
      for (int ntl = 0; ntl < 2; ntl++) {
        int j = (2 * w + ntl) * 16 + col;
        int chunkj = j >> 3;
        float b2v = ntl ? b2r1 : b2r0;
#pragma unroll
        for (int r = 0; r < 4; r++) {
          int p = quad * 4 + r;
          float z2 = acc[0][ntl][r] + b2v;
          float d0 = acc[1][ntl][r], d1 = acc[2][ntl][r], d2 = acc[3][ntl][r];
          float Av = acc[4][ntl][r];
          float t2 = mytanh(z2);
          float s2 = 1.0f - t2 * t2;
          float gg = s2 * (Av - 2.0f * t2 * (d0 * d0 + d1 * d1 + d2 * d2));
          int base = ((chunkj ^ p) << 3) + (j & 7);
          hg[p * 128 + base]        = (_Float16)t2;   // h2 rows 0..15
          hg[(16 + p) * 128 + base] = (_Float16)gg;   // G  rows 16..31
        }
      }
    }
    __syncthreads();  // the ONE barrier per pass
  }

  // ---- epilogue: D+E for the final pass (its C completed before last bar) ----
  if (w < 2) phaseDE(parity ^ 1);

  // ---- final: wave reduce, one atomic per wave ----
#pragma unroll
  for (int off = 32; off > 0; off >>= 1)
    wsum += __shfl_down(wsum, off, 64);
  if (l == 0)
    atomicAdd(out, wsum * (1.0f / ((float)NPTS * (float)(FCH - 1))));
}

extern "C" void kernel_launch(void* const* d_in, const int* in_sizes, int n_in,
                              void* d_out, int out_size, void* d_ws, size_t ws_size,
                              hipStream_t stream) {
  const float* x     = (const float*)d_in[0];
  const float* omega = (const float*)d_in[1];
  const float* W1    = (const float*)d_in[2];
  const float* b1    = (const float*)d_in[3];
  const float* W2    = (const float*)d_in[4];
  const float* b2    = (const float*)d_in[5];
  const float* W3    = (const float*)d_in[6];
  const float* b3    = (const float*)d_in[7];
  float* out = (float*)d_out;

  (void)hipMemsetAsync(out, 0, sizeof(float), stream);
  helmholtz_kernel<<<GRID, BLOCK, 0, stream>>>(x, omega, W1, b1, W2, b2, W3, b3, out);
}